// Round 1
// 211.414 us; speedup vs baseline: 1.0421x; 1.0421x over previous
//
#include <hip/hip_runtime.h>
#include <cmath>

#define NB 256
#define NS 8192
#define NF 2048
#define NK 20

typedef _Float16 half8 __attribute__((ext_vector_type(8)));
typedef _Float16 half4 __attribute__((ext_vector_type(4)));
typedef float f32x4 __attribute__((ext_vector_type(4)));

__device__ __forceinline__ void async16(const void* g, void* l) {
  __builtin_amdgcn_global_load_lds(
      (const __attribute__((address_space(1))) unsigned int*)g,
      (__attribute__((address_space(3))) unsigned int*)l, 16, 0, 0);
}

__device__ __forceinline__ float waveSum(float v) {
#pragma unroll
  for (int off = 32; off > 0; off >>= 1) v += __shfl_xor(v, off, 64);
  return v;
}
__device__ __forceinline__ float waveMax(float v) {
#pragma unroll
  for (int off = 32; off > 0; off >>= 1) v = fmaxf(v, __shfl_xor(v, off, 64));
  return v;
}

// ============ K1: prep (everything independent, one dispatch) ============
// blocks [0,8192): features row copy -> out (+momentum winner rows) + fp16 fh
// blocks [8192,8704): row stats -> mll, alpha_h
// blocks [8704,9216): Pt transpose (16 cols/block), RAW exp fp16
// blocks [9216,9472): normalize x -> xh fp16
// block 9472: zero Wp + build neighbor-weight rows + zero loss accumulators
__global__ __launch_bounds__(256, 1) void prep(
    const float4* __restrict__ f4, const float* __restrict__ in0,
    const float* __restrict__ logits0, const float* __restrict__ logits1,
    const int* __restrict__ targets, const int* __restrict__ neighbors,
    const float* __restrict__ ndist,
    float* __restrict__ outF, _Float16* __restrict__ fh,
    _Float16* __restrict__ Pt, _Float16* __restrict__ xh,
    _Float16* __restrict__ alpha_h, float* __restrict__ mll,
    _Float16* __restrict__ Wp, float* __restrict__ loss) {
  __shared__ alignas(16) union {
    struct {
      float redA[4];
      float redB[4];
      unsigned long long wmask[4];
    } s;
    _Float16 Lt[16 * 520];  // 16.25 KB -> 8 blocks/CU (wave-capped), was 33 KB
  } sm;
  int tid = threadIdx.x, blk = blockIdx.x;
  int wave = tid >> 6, lane = tid & 63;

  if (blk < NS) {
    // ---- features row ----
    int row = blk;
    const float4* fr = f4 + (size_t)row * (NF / 4);
    float4 v0 = fr[tid], v1 = fr[tid + 256];
    half4 h0, h1;
    h0[0] = (_Float16)v0.x; h0[1] = (_Float16)v0.y; h0[2] = (_Float16)v0.z; h0[3] = (_Float16)v0.w;
    h1[0] = (_Float16)v1.x; h1[1] = (_Float16)v1.y; h1[2] = (_Float16)v1.z; h1[3] = (_Float16)v1.w;
    ((half4*)(fh + (size_t)row * NF))[tid] = h0;
    ((half4*)(fh + (size_t)row * NF))[tid + 256] = h1;
    // winner = last b with targets[b]==row (ballot, no O(B^2) scan)
    unsigned long long mk = __ballot(targets[tid] == row);
    if (lane == 0) sm.s.wmask[wave] = mk;
    __syncthreads();
    int u = -1;
#pragma unroll
    for (int w = 3; w >= 0; --w)
      if (u < 0 && sm.s.wmask[w])
        u = w * 64 + 63 - (int)__clzll(sm.s.wmask[w]);
    if (u >= 0) {  // block-uniform
      const float4* xr = (const float4*)(in0 + (size_t)u * NF);
      float4 a0 = xr[tid], a1 = xr[tid + 256];
      float ssx = a0.x * a0.x + a0.y * a0.y + a0.z * a0.z + a0.w * a0.w +
                  a1.x * a1.x + a1.y * a1.y + a1.z * a1.z + a1.w * a1.w;
      float w1 = waveSum(ssx);
      if (lane == 0) sm.s.redA[wave] = w1;
      __syncthreads();
      float totx = (sm.s.redA[0] + sm.s.redA[1]) + (sm.s.redA[2] + sm.s.redA[3]);
      float ix = 0.8f / fmaxf(sqrtf(totx), 1e-12f);  // fold 0.8 into inv-norm
      v0 = make_float4(0.2f * v0.x + ix * a0.x, 0.2f * v0.y + ix * a0.y,
                       0.2f * v0.z + ix * a0.z, 0.2f * v0.w + ix * a0.w);
      v1 = make_float4(0.2f * v1.x + ix * a1.x, 0.2f * v1.y + ix * a1.y,
                       0.2f * v1.z + ix * a1.z, 0.2f * v1.w + ix * a1.w);
      float ss = v0.x * v0.x + v0.y * v0.y + v0.z * v0.z + v0.w * v0.w +
                 v1.x * v1.x + v1.y * v1.y + v1.z * v1.z + v1.w * v1.w;
      float w2 = waveSum(ss);
      if (lane == 0) sm.s.redB[wave] = w2;
      __syncthreads();
      float tot = (sm.s.redB[0] + sm.s.redB[1]) + (sm.s.redB[2] + sm.s.redB[3]);
      float inv = 1.0f / fmaxf(sqrtf(tot), 1e-12f);
      v0.x *= inv; v0.y *= inv; v0.z *= inv; v0.w *= inv;
      v1.x *= inv; v1.y *= inv; v1.z *= inv; v1.w *= inv;
    }
    float4* o4 = (float4*)(outF + (size_t)row * NF);
    o4[tid] = v0;
    o4[tid + 256] = v1;
  } else if (blk < NS + 512) {
    // ---- row stats ----
    int r = blk - NS;
    const float* src = (r < NB) ? logits0 : logits1;
    const float4* row = (const float4*)(src + (size_t)(r & (NB - 1)) * NS);
    float4 v[8];
    float mx = -1e30f;
#pragma unroll
    for (int i = 0; i < 8; ++i) {
      v[i] = row[tid + i * 256];
      mx = fmaxf(mx, fmaxf(fmaxf(v[i].x, v[i].y), fmaxf(v[i].z, v[i].w)));
    }
    float wv = waveMax(mx);
    if (lane == 0) sm.s.redA[wave] = wv;
    __syncthreads();
    float m = fmaxf(fmaxf(sm.s.redA[0], sm.s.redA[1]), fmaxf(sm.s.redA[2], sm.s.redA[3]));
    float se = 0.0f;
#pragma unroll
    for (int i = 0; i < 8; ++i)
      se += expf(v[i].x - m) + expf(v[i].y - m) + expf(v[i].z - m) + expf(v[i].w - m);
    float sw = waveSum(se);
    if (lane == 0) sm.s.redB[wave] = sw;
    __syncthreads();
    float l = (sm.s.redB[0] + sm.s.redB[1]) + (sm.s.redB[2] + sm.s.redB[3]);
    if (tid == 0) {
      mll[r] = m + logf(l);
      alpha_h[r] = (_Float16)(256.0f * expf(-m) / l);
    }
  } else if (blk < NS + 1024) {
    // ---- Pt transpose (raw exp), 16 columns per block ----
    int s0 = (blk - (NS + 512)) * 16;
#pragma unroll
    for (int g = 0; g < 8; ++g) {
      int pos = g * 256 + tid;
      int row = pos >> 2, c4 = pos & 3;
      const float* src = ((row < NB) ? logits0 + (size_t)row * NS
                                     : logits1 + (size_t)(row - NB) * NS) + s0 + c4 * 4;
      float4 v = *(const float4*)src;
      sm.Lt[(c4 * 4 + 0) * 520 + row] = (_Float16)expf(v.x);
      sm.Lt[(c4 * 4 + 1) * 520 + row] = (_Float16)expf(v.y);
      sm.Lt[(c4 * 4 + 2) * 520 + row] = (_Float16)expf(v.z);
      sm.Lt[(c4 * 4 + 3) * 520 + row] = (_Float16)expf(v.w);
    }
    __syncthreads();
    int srow = tid >> 4, seg = tid & 15;
    _Float16* dst = Pt + (size_t)(s0 + srow) * 512 + seg * 32;
    const _Float16* lsrc = &sm.Lt[srow * 520 + seg * 32];
#pragma unroll
    for (int q = 0; q < 4; ++q)
      *(half8*)(dst + q * 8) = *(const half8*)(lsrc + q * 8);
  } else if (blk < NS + 1280) {
    // ---- normalize x -> xh ----
    int b = blk - (NS + 1024);
    const float4* row = (const float4*)(in0 + (size_t)b * NF);
    float4 v0 = row[tid], v1 = row[tid + 256];
    float ss = v0.x * v0.x + v0.y * v0.y + v0.z * v0.z + v0.w * v0.w +
               v1.x * v1.x + v1.y * v1.y + v1.z * v1.z + v1.w * v1.w;
    float w = waveSum(ss);
    if (lane == 0) sm.s.redA[wave] = w;
    __syncthreads();
    float tot = (sm.s.redA[0] + sm.s.redA[1]) + (sm.s.redA[2] + sm.s.redA[3]);
    float inv = 1.0f / fmaxf(sqrtf(tot), 1e-12f);
    half4 h0, h1;
    h0[0] = (_Float16)(v0.x * inv); h0[1] = (_Float16)(v0.y * inv);
    h0[2] = (_Float16)(v0.z * inv); h0[3] = (_Float16)(v0.w * inv);
    h1[0] = (_Float16)(v1.x * inv); h1[1] = (_Float16)(v1.y * inv);
    h1[2] = (_Float16)(v1.z * inv); h1[3] = (_Float16)(v1.w * inv);
    ((half4*)(xh + (size_t)b * NF))[tid] = h0;
    ((half4*)(xh + (size_t)b * NF))[tid + 256] = h1;
  } else {
    // ---- weight-matrix build (one block, registers only) ----
    if (tid < 3) loss[tid] = 0.0f;  // zero loss accumulators for K3 atomics
    float4* W4 = (float4*)Wp;
    for (int i = tid; i < 512 * 512 * 2 / 16; i += 256) W4[i] = make_float4(0, 0, 0, 0);
    __syncthreads();
    int b = tid;
    float d[NK], e[NK];
    int n[NK];
    float s = 0.0f;
    int cnt = 0;
#pragma unroll
    for (int k = 0; k < NK; ++k) {
      d[k] = ndist[b * NK + k];
      n[k] = neighbors[b * NK + k];
      e[k] = expf(d[k] * (1.0f / 0.6f));
      s += e[k];
      cnt += (d[k] <= 2.0f) ? 1 : 0;
    }
    float invs = 1.0f / (2.0f * s);
    float invc = 1.0f / fmaxf((float)cnt, 1.0f);
    _Float16* rkl = Wp + (size_t)b * 512;
    _Float16* rce = Wp + (size_t)(256 + b) * 512;
#pragma unroll
    for (int k = 0; k < NK; ++k) {
      bool first = true;
#pragma unroll
      for (int k2 = 0; k2 < NK; ++k2)
        if (k2 < k && n[k2] == n[k]) first = false;
      if (first) {
        float wsum = 0.0f, ksum = 0.0f;
#pragma unroll
        for (int k2 = 0; k2 < NK; ++k2)
          if (k2 >= k && n[k2] == n[k]) {
            wsum += e[k2] * invs;
            ksum += (d[k2] <= 2.0f) ? invc : 0.0f;
          }
        rkl[n[k]] = (_Float16)ksum;
        rce[n[k]] = (_Float16)wsum;
        rce[256 + n[k]] = (_Float16)wsum;
      }
    }
  }
}

// ============ K2: both GEMMs ============
// blocks [0,256): scores = x@F^T fused stripe-LSE + target pick (128x64, BK=64)
// blocks [256,512): T = W@P fused CE/KL epilogue (128x128, BK=64, alpha B-scale)
__global__ __launch_bounds__(256) void gemms(
    const _Float16* __restrict__ xh, const _Float16* __restrict__ fh,
    const _Float16* __restrict__ Wp, const _Float16* __restrict__ Pt,
    const _Float16* __restrict__ alpha_h,
    const float* __restrict__ logits0, const float* __restrict__ logits1,
    const float* __restrict__ mll, const int* __restrict__ targets,
    float* __restrict__ pm, float* __restrict__ pl, float* __restrict__ tgt,
    float* __restrict__ part) {
  __shared__ alignas(16) _Float16 As[128 * 64];
  __shared__ alignas(16) _Float16 Bs[128 * 64];
  __shared__ alignas(16) _Float16 Al[512];
  __shared__ float red[4];
  int tid = threadIdx.x, wave = tid >> 6, lane = tid & 63;
  int quad = lane >> 4, r16 = lane & 15, lrow = lane >> 3, lch = lane & 7;
  int blk = blockIdx.x;
  if (blk < 256) {
    int bx = blk & 127, by = blk >> 7;
    int n0 = bx * 64, m0 = by * 128;
    f32x4 acc[2][4] = {};
    for (int k0 = 0; k0 < NF; k0 += 64) {
      __syncthreads();
#pragma unroll
      for (int ss = 0; ss < 4; ++ss) {
        int rl = ss * 32 + wave * 8 + lrow;
        int sc = lch ^ (rl & 7);
        async16(xh + (size_t)(m0 + rl) * NF + k0 + sc * 8, &As[rl * 64 + lch * 8]);
      }
#pragma unroll
      for (int ss = 0; ss < 2; ++ss) {
        int rl = ss * 32 + wave * 8 + lrow;
        int sc = lch ^ (rl & 7);
        async16(fh + (size_t)(n0 + rl) * NF + k0 + sc * 8, &Bs[rl * 64 + lch * 8]);
      }
      __syncthreads();
#pragma unroll
      for (int sub = 0; sub < 2; ++sub) {
        int slot = ((sub * 4 + quad) ^ (r16 & 7)) * 8;
        half8 af[2], bf[4];
#pragma unroll
        for (int i = 0; i < 2; ++i)
          af[i] = *(const half8*)&As[(wave * 32 + i * 16 + r16) * 64 + slot];
#pragma unroll
        for (int j = 0; j < 4; ++j)
          bf[j] = *(const half8*)&Bs[(j * 16 + r16) * 64 + slot];
#pragma unroll
        for (int i = 0; i < 2; ++i)
#pragma unroll
          for (int j = 0; j < 4; ++j)
            acc[i][j] = __builtin_amdgcn_mfma_f32_16x16x32_f16(af[i], bf[j], acc[i][j], 0, 0, 0);
      }
    }
#pragma unroll
    for (int i = 0; i < 2; ++i)
#pragma unroll
      for (int r = 0; r < 4; ++r) {
        int R = m0 + wave * 32 + i * 16 + quad * 4 + r;
        float sv[4];
#pragma unroll
        for (int j = 0; j < 4; ++j) sv[j] = acc[i][j][r] * 20.0f;  // 1/TEMP
        float mx = fmaxf(fmaxf(sv[0], sv[1]), fmaxf(sv[2], sv[3]));
#pragma unroll
        for (int m2 = 1; m2 < 16; m2 <<= 1) mx = fmaxf(mx, __shfl_xor(mx, m2, 64));
        float e = expf(sv[0] - mx) + expf(sv[1] - mx) + expf(sv[2] - mx) + expf(sv[3] - mx);
#pragma unroll
        for (int m2 = 1; m2 < 16; m2 <<= 1) e += __shfl_xor(e, m2, 64);
        int tg = targets[R];
#pragma unroll
        for (int j = 0; j < 4; ++j)
          if (n0 + j * 16 + r16 == tg) tgt[R] = sv[j];
        if (r16 == 0) { pm[R * 128 + bx] = mx; pl[R * 128 + bx] = e; }
      }
  } else {
    int nb = blk - 256;
    int bx = nb & 63, by = nb >> 6;
    int n0 = bx * 128, m0 = by * 128;
    int wm = (wave >> 1) * 64, wn = (wave & 1) * 64;
    if (tid < 64) ((half8*)Al)[tid] = ((const half8*)alpha_h)[tid];
    f32x4 acc[4][4] = {};
    for (int k0 = 0; k0 < 512; k0 += 64) {
      __syncthreads();
#pragma unroll
      for (int ss = 0; ss < 4; ++ss) {
        int rl = ss * 32 + wave * 8 + lrow;
        int sc = lch ^ (rl & 7);
        async16(Wp + (size_t)(m0 + rl) * 512 + k0 + sc * 8, &As[rl * 64 + lch * 8]);
        async16(Pt + (size_t)(n0 + rl) * 512 + k0 + sc * 8, &Bs[rl * 64 + lch * 8]);
      }
      __syncthreads();
#pragma unroll
      for (int sub = 0; sub < 2; ++sub) {
        int slot = ((sub * 4 + quad) ^ (r16 & 7)) * 8;
        half8 alv = *(const half8*)&Al[k0 + slot];
        half8 af[4], bf[4];
#pragma unroll
        for (int i = 0; i < 4; ++i)
          af[i] = *(const half8*)&As[(wm + i * 16 + r16) * 64 + slot];
#pragma unroll
        for (int j = 0; j < 4; ++j)
          bf[j] = *(const half8*)&Bs[(wn + j * 16 + r16) * 64 + slot] * alv;
#pragma unroll
        for (int i = 0; i < 4; ++i)
#pragma unroll
          for (int j = 0; j < 4; ++j)
            acc[i][j] = __builtin_amdgcn_mfma_f32_16x16x32_f16(af[i], bf[j], acc[i][j], 0, 0, 0);
      }
    }
    bool iskl = (by < 2);
    const float* lgbase = iskl ? logits1 : logits0;
    float local = 0.0f;
#pragma unroll
    for (int i = 0; i < 4; ++i)
#pragma unroll
      for (int r = 0; r < 4; ++r) {
        int Mg = m0 + wm + i * 16 + quad * 4 + r;
        int b = iskl ? Mg : (Mg - 256);
        float mv = mll[iskl ? 256 + b : b];
        const float* lgrow = lgbase + (size_t)b * NS + n0 + wn;
#pragma unroll
        for (int j = 0; j < 4; ++j) {
          float lg = lgrow[j * 16 + r16];
          float t = acc[i][j][r] * (1.0f / 256.0f);
          if (iskl)
            local += (t > 0.0f) ? t * (logf(fmaxf(t, 1e-12f)) - (lg - mv)) : 0.0f;
          else
            local += -0.1f * t * (lg - mv);
        }
      }
    float wsv = waveSum(local);
    if (lane == 0) red[wave] = wsv;
    __syncthreads();
    if (tid == 0) part[nb] = (red[0] + red[1]) + (red[2] + red[3]);
  }
}

// ============ K3: finalize (256 blocks, coalesced, atomic accumulate) ============
// block b: LSE over the 128 stripes of row b (coalesced reads) + this row's
// CE-onehot term + its part[] contribution -> atomicAdd into out[0..2]
// (out[0..2] zeroed by prep's tail block; stream order guarantees visibility).
__global__ __launch_bounds__(128) void final_reduce(
    const float* __restrict__ pm, const float* __restrict__ pl,
    const float* __restrict__ tgt, const float* __restrict__ part,
    const float* __restrict__ logits0, const float* __restrict__ mll,
    const int* __restrict__ targets, const float* __restrict__ rampup,
    float* __restrict__ out) {
  __shared__ float rmx[2], rsm[2];
  int tid = threadIdx.x;
  int b = blockIdx.x;
  float m = pm[b * 128 + tid];
  float l = pl[b * 128 + tid];
  float wm = waveMax(m);
  if ((tid & 63) == 0) rmx[tid >> 6] = wm;
  __syncthreads();
  float mx = fmaxf(rmx[0], rmx[1]);
  float e = l * expf(m - mx);
  float ws = waveSum(e);
  if ((tid & 63) == 0) rsm[tid >> 6] = ws;
  __syncthreads();
  if (tid == 0) {
    float S = rsm[0] + rsm[1];
    float nce = -(tgt[b] - mx - logf(S));
    int tg = targets[b];
    float oh = -0.9f * (logits0[(size_t)b * NS + tg] - mll[b]);
    float pb = part[b];
    float v1 = oh;
    if (b >= 128) v1 += pb;  // CE partials live at part[128..255]
    atomicAdd(out + 0, nce * (1.0f / 256.0f));
    atomicAdd(out + 1, v1 * (1.0f / 256.0f));
    if (b < 128) atomicAdd(out + 2, rampup[0] * pb * (1.0f / 256.0f));
  }
}

extern "C" void kernel_launch(void* const* d_in, const int* in_sizes, int n_in,
                              void* d_out, int out_size, void* d_ws, size_t ws_size,
                              hipStream_t stream) {
  const float* inputs0 = (const float*)d_in[0];
  const float* logits0 = (const float*)d_in[1];
  const float* logits1 = (const float*)d_in[2];
  const int* targets = (const int*)d_in[3];
  const int* neighbors = (const int*)d_in[5];
  const float* ndist = (const float*)d_in[6];
  const float* rampup = (const float*)d_in[7];
  const float* features = (const float*)d_in[8];
  float* out = (float*)d_out;

  char* ws = (char*)d_ws;
  float* mll = (float*)(ws + 4096);             // 2 KB
  _Float16* alpha_h = (_Float16*)(ws + 8192);   // 1 KB
  float* part = (float*)(ws + 12288);           // 1 KB
  float* tgt = (float*)(ws + 16384);            // 1 KB
  float* pm = (float*)(ws + 65536);             // 128 KB
  float* pl = (float*)(ws + 196608);            // 128 KB
  _Float16* Wp = (_Float16*)(ws + 524288);      // 512 KB
  _Float16* xh = (_Float16*)(ws + (3 << 20));   // 1 MB
  _Float16* Pt = (_Float16*)(ws + (4 << 20));   // 8 MB
  _Float16* fh = (_Float16*)(ws + (12 << 20));  // 32 MB

  prep<<<NS + 1281, 256, 0, stream>>>((const float4*)features, inputs0, logits0,
                                      logits1, targets, neighbors, ndist,
                                      out + 3, fh, Pt, xh, alpha_h, mll, Wp, out);
  gemms<<<512, 256, 0, stream>>>(xh, fh, Wp, Pt, alpha_h, logits0, logits1, mll,
                                 targets, pm, pl, tgt, part);
  final_reduce<<<256, 128, 0, stream>>>(pm, pl, tgt, part, logits0, mll, targets,
                                        rampup, out);
}

// Round 2
// 209.924 us; speedup vs baseline: 1.0495x; 1.0071x over previous
//
#include <hip/hip_runtime.h>
#include <cmath>

#define NB 256
#define NS 8192
#define NF 2048
#define NK 20

typedef _Float16 half8 __attribute__((ext_vector_type(8)));
typedef _Float16 half4 __attribute__((ext_vector_type(4)));
typedef float f32x4 __attribute__((ext_vector_type(4)));

__device__ __forceinline__ void async16(const void* g, void* l) {
  __builtin_amdgcn_global_load_lds(
      (const __attribute__((address_space(1))) unsigned int*)g,
      (__attribute__((address_space(3))) unsigned int*)l, 16, 0, 0);
}

__device__ __forceinline__ float waveSum(float v) {
#pragma unroll
  for (int off = 32; off > 0; off >>= 1) v += __shfl_xor(v, off, 64);
  return v;
}
__device__ __forceinline__ float waveMax(float v) {
#pragma unroll
  for (int off = 32; off > 0; off >>= 1) v = fmaxf(v, __shfl_xor(v, off, 64));
  return v;
}

// ============ K1: prep (small now — copy fused into gemms) ============
// blocks [0,512): row stats -> mll, alpha_h
// blocks [512,1024): Pt transpose (16 cols/block), RAW exp fp16
// blocks [1024,1280): normalize x -> xh fp16
// block 1280: zero Wp + build neighbor-weight rows + zero loss accumulators
__global__ __launch_bounds__(256, 1) void prep(
    const float* __restrict__ in0, const float* __restrict__ logits0,
    const float* __restrict__ logits1, const int* __restrict__ neighbors,
    const float* __restrict__ ndist, _Float16* __restrict__ Pt,
    _Float16* __restrict__ xh, _Float16* __restrict__ alpha_h,
    float* __restrict__ mll, _Float16* __restrict__ Wp,
    float* __restrict__ loss) {
  __shared__ alignas(16) union {
    struct {
      float redA[4];
      float redB[4];
    } s;
    _Float16 Lt[16 * 520];  // 16.25 KB
  } sm;
  int tid = threadIdx.x, blk = blockIdx.x;
  int wave = tid >> 6, lane = tid & 63;

  if (blk < 512) {
    // ---- row stats ----
    int r = blk;
    const float* src = (r < NB) ? logits0 : logits1;
    const float4* row = (const float4*)(src + (size_t)(r & (NB - 1)) * NS);
    float4 v[8];
    float mx = -1e30f;
#pragma unroll
    for (int i = 0; i < 8; ++i) {
      v[i] = row[tid + i * 256];
      mx = fmaxf(mx, fmaxf(fmaxf(v[i].x, v[i].y), fmaxf(v[i].z, v[i].w)));
    }
    float wv = waveMax(mx);
    if (lane == 0) sm.s.redA[wave] = wv;
    __syncthreads();
    float m = fmaxf(fmaxf(sm.s.redA[0], sm.s.redA[1]), fmaxf(sm.s.redA[2], sm.s.redA[3]));
    float se = 0.0f;
#pragma unroll
    for (int i = 0; i < 8; ++i)
      se += expf(v[i].x - m) + expf(v[i].y - m) + expf(v[i].z - m) + expf(v[i].w - m);
    float sw = waveSum(se);
    if (lane == 0) sm.s.redB[wave] = sw;
    __syncthreads();
    float l = (sm.s.redB[0] + sm.s.redB[1]) + (sm.s.redB[2] + sm.s.redB[3]);
    if (tid == 0) {
      mll[r] = m + logf(l);
      alpha_h[r] = (_Float16)(256.0f * expf(-m) / l);
    }
  } else if (blk < 1024) {
    // ---- Pt transpose (raw exp), 16 columns per block ----
    int s0 = (blk - 512) * 16;
#pragma unroll
    for (int g = 0; g < 8; ++g) {
      int pos = g * 256 + tid;
      int row = pos >> 2, c4 = pos & 3;
      const float* src = ((row < NB) ? logits0 + (size_t)row * NS
                                     : logits1 + (size_t)(row - NB) * NS) + s0 + c4 * 4;
      float4 v = *(const float4*)src;
      sm.Lt[(c4 * 4 + 0) * 520 + row] = (_Float16)expf(v.x);
      sm.Lt[(c4 * 4 + 1) * 520 + row] = (_Float16)expf(v.y);
      sm.Lt[(c4 * 4 + 2) * 520 + row] = (_Float16)expf(v.z);
      sm.Lt[(c4 * 4 + 3) * 520 + row] = (_Float16)expf(v.w);
    }
    __syncthreads();
    int srow = tid >> 4, seg = tid & 15;
    _Float16* dst = Pt + (size_t)(s0 + srow) * 512 + seg * 32;
    const _Float16* lsrc = &sm.Lt[srow * 520 + seg * 32];
#pragma unroll
    for (int q = 0; q < 4; ++q)
      *(half8*)(dst + q * 8) = *(const half8*)(lsrc + q * 8);
  } else if (blk < 1280) {
    // ---- normalize x -> xh ----
    int b = blk - 1024;
    const float4* row = (const float4*)(in0 + (size_t)b * NF);
    float4 v0 = row[tid], v1 = row[tid + 256];
    float ss = v0.x * v0.x + v0.y * v0.y + v0.z * v0.z + v0.w * v0.w +
               v1.x * v1.x + v1.y * v1.y + v1.z * v1.z + v1.w * v1.w;
    float w = waveSum(ss);
    if (lane == 0) sm.s.redA[wave] = w;
    __syncthreads();
    float tot = (sm.s.redA[0] + sm.s.redA[1]) + (sm.s.redA[2] + sm.s.redA[3]);
    float inv = 1.0f / fmaxf(sqrtf(tot), 1e-12f);
    half4 h0, h1;
    h0[0] = (_Float16)(v0.x * inv); h0[1] = (_Float16)(v0.y * inv);
    h0[2] = (_Float16)(v0.z * inv); h0[3] = (_Float16)(v0.w * inv);
    h1[0] = (_Float16)(v1.x * inv); h1[1] = (_Float16)(v1.y * inv);
    h1[2] = (_Float16)(v1.z * inv); h1[3] = (_Float16)(v1.w * inv);
    ((half4*)(xh + (size_t)b * NF))[tid] = h0;
    ((half4*)(xh + (size_t)b * NF))[tid + 256] = h1;
  } else {
    // ---- weight-matrix build (one block, registers only) ----
    if (tid < 3) loss[tid] = 0.0f;  // zero loss accumulators for K3 atomics
    float4* W4 = (float4*)Wp;
    for (int i = tid; i < 512 * 512 * 2 / 16; i += 256) W4[i] = make_float4(0, 0, 0, 0);
    __syncthreads();
    int b = tid;
    float d[NK], e[NK];
    int n[NK];
    float s = 0.0f;
    int cnt = 0;
#pragma unroll
    for (int k = 0; k < NK; ++k) {
      d[k] = ndist[b * NK + k];
      n[k] = neighbors[b * NK + k];
      e[k] = expf(d[k] * (1.0f / 0.6f));
      s += e[k];
      cnt += (d[k] <= 2.0f) ? 1 : 0;
    }
    float invs = 1.0f / (2.0f * s);
    float invc = 1.0f / fmaxf((float)cnt, 1.0f);
    _Float16* rkl = Wp + (size_t)b * 512;
    _Float16* rce = Wp + (size_t)(256 + b) * 512;
#pragma unroll
    for (int k = 0; k < NK; ++k) {
      bool first = true;
#pragma unroll
      for (int k2 = 0; k2 < NK; ++k2)
        if (k2 < k && n[k2] == n[k]) first = false;
      if (first) {
        float wsum = 0.0f, ksum = 0.0f;
#pragma unroll
        for (int k2 = 0; k2 < NK; ++k2)
          if (k2 >= k && n[k2] == n[k]) {
            wsum += e[k2] * invs;
            ksum += (d[k2] <= 2.0f) ? invc : 0.0f;
          }
        rkl[n[k]] = (_Float16)ksum;
        rce[n[k]] = (_Float16)wsum;
        rce[256 + n[k]] = (_Float16)wsum;
      }
    }
  }
}

// ============ K2: both GEMMs ============
// blocks [0,256): scores = x@F^T, B = fp32 features reg-staged->fp16 LDS;
//                 by==0 blocks also stream the features tile to outF (copy).
//                 fused stripe-LSE + target pick (128x64, BK=64)
// blocks [256,512): T = W@P fused CE/KL epilogue (128x128, BK=64, alpha B-scale)
__global__ __launch_bounds__(256) void gemms(
    const _Float16* __restrict__ xh, const float* __restrict__ fB,
    const _Float16* __restrict__ Wp, const _Float16* __restrict__ Pt,
    const _Float16* __restrict__ alpha_h,
    const float* __restrict__ logits0, const float* __restrict__ logits1,
    const float* __restrict__ mll, const int* __restrict__ targets,
    float* __restrict__ outF, float* __restrict__ pm, float* __restrict__ pl,
    float* __restrict__ tgt, float* __restrict__ part) {
  __shared__ alignas(16) _Float16 As[128 * 64];
  __shared__ alignas(16) _Float16 Bs[128 * 64];
  __shared__ alignas(16) _Float16 Al[512];
  __shared__ float red[4];
  int tid = threadIdx.x, wave = tid >> 6, lane = tid & 63;
  int quad = lane >> 4, r16 = lane & 15, lrow = lane >> 3, lch = lane & 7;
  int blk = blockIdx.x;
  if (blk < 256) {
    int bx = blk & 127, by = blk >> 7;
    int n0 = bx * 64, m0 = by * 128;
    int c4 = tid & 15, rbase = tid >> 4;  // B-staging: row = ss*16+rbase, col4 = c4
    f32x4 acc[2][4] = {};
    for (int k0 = 0; k0 < NF; k0 += 64) {
      // issue fp32 B loads early (regs only, no LDS hazard)
      float4 bv[4];
#pragma unroll
      for (int ss = 0; ss < 4; ++ss)
        bv[ss] = *(const float4*)(fB + (size_t)(n0 + ss * 16 + rbase) * NF + k0 + c4 * 4);
      __syncthreads();
#pragma unroll
      for (int ss = 0; ss < 4; ++ss) {
        int rl = ss * 32 + wave * 8 + lrow;
        int sc = lch ^ (rl & 7);
        async16(xh + (size_t)(m0 + rl) * NF + k0 + sc * 8, &As[rl * 64 + lch * 8]);
      }
#pragma unroll
      for (int ss = 0; ss < 4; ++ss) {
        int row = ss * 16 + rbase;
        half4 h;
        h[0] = (_Float16)bv[ss].x; h[1] = (_Float16)bv[ss].y;
        h[2] = (_Float16)bv[ss].z; h[3] = (_Float16)bv[ss].w;
        int pc = (((c4 >> 1) ^ (row & 7)) << 3) + ((c4 & 1) << 2);
        *(half4*)&Bs[row * 64 + pc] = h;
        if (by == 0)
          *(float4*)(outF + (size_t)(n0 + row) * NF + k0 + c4 * 4) = bv[ss];
      }
      __syncthreads();
#pragma unroll
      for (int sub = 0; sub < 2; ++sub) {
        int slot = ((sub * 4 + quad) ^ (r16 & 7)) * 8;
        half8 af[2], bf[4];
#pragma unroll
        for (int i = 0; i < 2; ++i)
          af[i] = *(const half8*)&As[(wave * 32 + i * 16 + r16) * 64 + slot];
#pragma unroll
        for (int j = 0; j < 4; ++j)
          bf[j] = *(const half8*)&Bs[(j * 16 + r16) * 64 + slot];
#pragma unroll
        for (int i = 0; i < 2; ++i)
#pragma unroll
          for (int j = 0; j < 4; ++j)
            acc[i][j] = __builtin_amdgcn_mfma_f32_16x16x32_f16(af[i], bf[j], acc[i][j], 0, 0, 0);
      }
    }
#pragma unroll
    for (int i = 0; i < 2; ++i)
#pragma unroll
      for (int r = 0; r < 4; ++r) {
        int R = m0 + wave * 32 + i * 16 + quad * 4 + r;
        float sv[4];
#pragma unroll
        for (int j = 0; j < 4; ++j) sv[j] = acc[i][j][r] * 20.0f;  // 1/TEMP
        float mx = fmaxf(fmaxf(sv[0], sv[1]), fmaxf(sv[2], sv[3]));
#pragma unroll
        for (int m2 = 1; m2 < 16; m2 <<= 1) mx = fmaxf(mx, __shfl_xor(mx, m2, 64));
        float e = expf(sv[0] - mx) + expf(sv[1] - mx) + expf(sv[2] - mx) + expf(sv[3] - mx);
#pragma unroll
        for (int m2 = 1; m2 < 16; m2 <<= 1) e += __shfl_xor(e, m2, 64);
        int tg = targets[R];
#pragma unroll
        for (int j = 0; j < 4; ++j)
          if (n0 + j * 16 + r16 == tg) tgt[R] = sv[j];
        if (r16 == 0) { pm[R * 128 + bx] = mx; pl[R * 128 + bx] = e; }
      }
  } else {
    int nb = blk - 256;
    int bx = nb & 63, by = nb >> 6;
    int n0 = bx * 128, m0 = by * 128;
    int wm = (wave >> 1) * 64, wn = (wave & 1) * 64;
    if (tid < 64) ((half8*)Al)[tid] = ((const half8*)alpha_h)[tid];
    f32x4 acc[4][4] = {};
    for (int k0 = 0; k0 < 512; k0 += 64) {
      __syncthreads();
#pragma unroll
      for (int ss = 0; ss < 4; ++ss) {
        int rl = ss * 32 + wave * 8 + lrow;
        int sc = lch ^ (rl & 7);
        async16(Wp + (size_t)(m0 + rl) * 512 + k0 + sc * 8, &As[rl * 64 + lch * 8]);
        async16(Pt + (size_t)(n0 + rl) * 512 + k0 + sc * 8, &Bs[rl * 64 + lch * 8]);
      }
      __syncthreads();
#pragma unroll
      for (int sub = 0; sub < 2; ++sub) {
        int slot = ((sub * 4 + quad) ^ (r16 & 7)) * 8;
        half8 alv = *(const half8*)&Al[k0 + slot];
        half8 af[4], bf[4];
#pragma unroll
        for (int i = 0; i < 4; ++i)
          af[i] = *(const half8*)&As[(wm + i * 16 + r16) * 64 + slot];
#pragma unroll
        for (int j = 0; j < 4; ++j)
          bf[j] = *(const half8*)&Bs[(wn + j * 16 + r16) * 64 + slot] * alv;
#pragma unroll
        for (int i = 0; i < 4; ++i)
#pragma unroll
          for (int j = 0; j < 4; ++j)
            acc[i][j] = __builtin_amdgcn_mfma_f32_16x16x32_f16(af[i], bf[j], acc[i][j], 0, 0, 0);
      }
    }
    bool iskl = (by < 2);
    const float* lgbase = iskl ? logits1 : logits0;
    float local = 0.0f;
#pragma unroll
    for (int i = 0; i < 4; ++i)
#pragma unroll
      for (int r = 0; r < 4; ++r) {
        int Mg = m0 + wm + i * 16 + quad * 4 + r;
        int b = iskl ? Mg : (Mg - 256);
        float mv = mll[iskl ? 256 + b : b];
        const float* lgrow = lgbase + (size_t)b * NS + n0 + wn;
#pragma unroll
        for (int j = 0; j < 4; ++j) {
          float lg = lgrow[j * 16 + r16];
          float t = acc[i][j][r] * (1.0f / 256.0f);
          if (iskl)
            local += (t > 0.0f) ? t * (logf(fmaxf(t, 1e-12f)) - (lg - mv)) : 0.0f;
          else
            local += -0.1f * t * (lg - mv);
        }
      }
    float wsv = waveSum(local);
    if (lane == 0) red[wave] = wsv;
    __syncthreads();
    if (tid == 0) part[nb] = (red[0] + red[1]) + (red[2] + red[3]);
  }
}

// ============ K3: finalize + momentum winner rows ============
// blocks [0,256): LSE over 128 stripes of row b + CE-onehot + part[] -> atomics
// blocks [256,512): block 256+b: if b is the LAST occurrence of targets[b],
//   recompute momentum+renorm row and overwrite outF[targets[b]] (runs after
//   gemms wrote the plain copy — stream order makes the clobber safe).
__global__ __launch_bounds__(128) void final_reduce(
    const float* __restrict__ pm, const float* __restrict__ pl,
    const float* __restrict__ tgt, const float* __restrict__ part,
    const float* __restrict__ logits0, const float* __restrict__ mll,
    const int* __restrict__ targets, const float* __restrict__ rampup,
    const float* __restrict__ in0, const float* __restrict__ features,
    float* __restrict__ outF, float* __restrict__ out) {
  __shared__ float rA[2], rB[2];
  __shared__ int flag;
  int tid = threadIdx.x, blk = blockIdx.x;
  if (blk < 256) {
    int b = blk;
    float m = pm[b * 128 + tid];
    float l = pl[b * 128 + tid];
    float wm = waveMax(m);
    if ((tid & 63) == 0) rA[tid >> 6] = wm;
    __syncthreads();
    float mx = fmaxf(rA[0], rA[1]);
    float e = l * expf(m - mx);
    float ws = waveSum(e);
    if ((tid & 63) == 0) rB[tid >> 6] = ws;
    __syncthreads();
    if (tid == 0) {
      float S = rB[0] + rB[1];
      float nce = -(tgt[b] - mx - logf(S));
      int tg = targets[b];
      float oh = -0.9f * (logits0[(size_t)b * NS + tg] - mll[b]);
      float pb = part[b];
      float v1 = oh;
      if (b >= 128) v1 += pb;  // CE partials live at part[128..255]
      atomicAdd(out + 0, nce * (1.0f / 256.0f));
      atomicAdd(out + 1, v1 * (1.0f / 256.0f));
      if (b < 128) atomicAdd(out + 2, rampup[0] * pb * (1.0f / 256.0f));
    }
  } else {
    int b = blk - 256;
    int tg = targets[b];
    if (tid == 0) flag = 0;
    __syncthreads();
    bool later = false;
    for (int i = b + 1 + tid; i < 256; i += 128) later = later || (targets[i] == tg);
    if (later) flag = 1;
    __syncthreads();
    if (flag) return;  // some later batch row owns this target
    const float4* xr = (const float4*)(in0 + (size_t)b * NF);
    const float4* fr = (const float4*)(features + (size_t)tg * NF);
    float4 a[4];
    float ssx = 0.0f;
#pragma unroll
    for (int s = 0; s < 4; ++s) {
      a[s] = xr[tid + s * 128];
      ssx += a[s].x * a[s].x + a[s].y * a[s].y + a[s].z * a[s].z + a[s].w * a[s].w;
    }
    float w1 = waveSum(ssx);
    if ((tid & 63) == 0) rA[tid >> 6] = w1;
    __syncthreads();
    float ix = 0.8f / fmaxf(sqrtf(rA[0] + rA[1]), 1e-12f);
    float4 v[4];
    float ss = 0.0f;
#pragma unroll
    for (int s = 0; s < 4; ++s) {
      float4 f = fr[tid + s * 128];
      v[s] = make_float4(0.2f * f.x + ix * a[s].x, 0.2f * f.y + ix * a[s].y,
                         0.2f * f.z + ix * a[s].z, 0.2f * f.w + ix * a[s].w);
      ss += v[s].x * v[s].x + v[s].y * v[s].y + v[s].z * v[s].z + v[s].w * v[s].w;
    }
    float w2 = waveSum(ss);
    if ((tid & 63) == 0) rB[tid >> 6] = w2;
    __syncthreads();
    float inv = 1.0f / fmaxf(sqrtf(rB[0] + rB[1]), 1e-12f);
    float4* o4 = (float4*)(outF + (size_t)tg * NF);
#pragma unroll
    for (int s = 0; s < 4; ++s)
      o4[tid + s * 128] = make_float4(v[s].x * inv, v[s].y * inv, v[s].z * inv, v[s].w * inv);
  }
}

extern "C" void kernel_launch(void* const* d_in, const int* in_sizes, int n_in,
                              void* d_out, int out_size, void* d_ws, size_t ws_size,
                              hipStream_t stream) {
  const float* inputs0 = (const float*)d_in[0];
  const float* logits0 = (const float*)d_in[1];
  const float* logits1 = (const float*)d_in[2];
  const int* targets = (const int*)d_in[3];
  const int* neighbors = (const int*)d_in[5];
  const float* ndist = (const float*)d_in[6];
  const float* rampup = (const float*)d_in[7];
  const float* features = (const float*)d_in[8];
  float* out = (float*)d_out;

  char* ws = (char*)d_ws;
  float* mll = (float*)(ws + 4096);             // 2 KB
  _Float16* alpha_h = (_Float16*)(ws + 8192);   // 1 KB
  float* part = (float*)(ws + 12288);           // 1 KB
  float* tgt = (float*)(ws + 16384);            // 1 KB
  float* pm = (float*)(ws + 65536);             // 128 KB
  float* pl = (float*)(ws + 196608);            // 128 KB
  _Float16* Wp = (_Float16*)(ws + 524288);      // 512 KB
  _Float16* xh = (_Float16*)(ws + (3 << 20));   // 1 MB
  _Float16* Pt = (_Float16*)(ws + (4 << 20));   // 8 MB

  prep<<<1281, 256, 0, stream>>>(inputs0, logits0, logits1, neighbors, ndist,
                                 Pt, xh, alpha_h, mll, Wp, out);
  gemms<<<512, 256, 0, stream>>>(xh, features, Wp, Pt, alpha_h, logits0, logits1,
                                 mll, targets, out + 3, pm, pl, tgt, part);
  final_reduce<<<512, 128, 0, stream>>>(pm, pl, tgt, part, logits0, mll, targets,
                                        rampup, inputs0, features, out + 3, out);
}

// Round 3
// 195.742 us; speedup vs baseline: 1.1255x; 1.0725x over previous
//
#include <hip/hip_runtime.h>
#include <cmath>

#define NB 256
#define NS 8192
#define NF 2048
#define NK 20

typedef _Float16 half8 __attribute__((ext_vector_type(8)));
typedef _Float16 half4 __attribute__((ext_vector_type(4)));
typedef float f32x4 __attribute__((ext_vector_type(4)));

__device__ __forceinline__ void async16(const void* g, void* l) {
  __builtin_amdgcn_global_load_lds(
      (const __attribute__((address_space(1))) unsigned int*)g,
      (__attribute__((address_space(3))) unsigned int*)l, 16, 0, 0);
}

__device__ __forceinline__ float waveSum(float v) {
#pragma unroll
  for (int off = 32; off > 0; off >>= 1) v += __shfl_xor(v, off, 64);
  return v;
}
__device__ __forceinline__ float waveMax(float v) {
#pragma unroll
  for (int off = 32; off > 0; off >>= 1) v = fmaxf(v, __shfl_xor(v, off, 64));
  return v;
}

// ============ K1: prep ============
// blocks [0,512): row stats -> mll, alpha_h   (block 0 also zeroes loss accums)
// blocks [512,1024): Pt transpose (16 cols/block), RAW exp fp16
// blocks [1024,1280): normalize x -> xh fp16
// blocks [1280,1536): block 1280+b zeroes Wp rows {b, 256+b} then builds the
//   neighbor-weight entries for batch item b (row ownership disjoint -> no race)
__global__ __launch_bounds__(256, 1) void prep(
    const float* __restrict__ in0, const float* __restrict__ logits0,
    const float* __restrict__ logits1, const int* __restrict__ neighbors,
    const float* __restrict__ ndist, _Float16* __restrict__ Pt,
    _Float16* __restrict__ xh, _Float16* __restrict__ alpha_h,
    float* __restrict__ mll, _Float16* __restrict__ Wp,
    float* __restrict__ loss) {
  __shared__ alignas(16) union {
    struct {
      float redA[4];
      float redB[4];
    } s;
    _Float16 Lt[16 * 520];  // 16.25 KB
  } sm;
  int tid = threadIdx.x, blk = blockIdx.x;
  int wave = tid >> 6, lane = tid & 63;

  if (blk < 512) {
    // ---- row stats ----
    if (blk == 0 && tid < 3) loss[tid] = 0.0f;
    int r = blk;
    const float* src = (r < NB) ? logits0 : logits1;
    const float4* row = (const float4*)(src + (size_t)(r & (NB - 1)) * NS);
    float4 v[8];
    float mx = -1e30f;
#pragma unroll
    for (int i = 0; i < 8; ++i) {
      v[i] = row[tid + i * 256];
      mx = fmaxf(mx, fmaxf(fmaxf(v[i].x, v[i].y), fmaxf(v[i].z, v[i].w)));
    }
    float wv = waveMax(mx);
    if (lane == 0) sm.s.redA[wave] = wv;
    __syncthreads();
    float m = fmaxf(fmaxf(sm.s.redA[0], sm.s.redA[1]), fmaxf(sm.s.redA[2], sm.s.redA[3]));
    float se = 0.0f;
#pragma unroll
    for (int i = 0; i < 8; ++i)
      se += expf(v[i].x - m) + expf(v[i].y - m) + expf(v[i].z - m) + expf(v[i].w - m);
    float sw = waveSum(se);
    if (lane == 0) sm.s.redB[wave] = sw;
    __syncthreads();
    float l = (sm.s.redB[0] + sm.s.redB[1]) + (sm.s.redB[2] + sm.s.redB[3]);
    if (tid == 0) {
      mll[r] = m + logf(l);
      alpha_h[r] = (_Float16)(256.0f * expf(-m) / l);
    }
  } else if (blk < 1024) {
    // ---- Pt transpose (raw exp), 16 columns per block ----
    int s0 = (blk - 512) * 16;
#pragma unroll
    for (int g = 0; g < 8; ++g) {
      int pos = g * 256 + tid;
      int row = pos >> 2, c4 = pos & 3;
      const float* src = ((row < NB) ? logits0 + (size_t)row * NS
                                     : logits1 + (size_t)(row - NB) * NS) + s0 + c4 * 4;
      float4 v = *(const float4*)src;
      sm.Lt[(c4 * 4 + 0) * 520 + row] = (_Float16)expf(v.x);
      sm.Lt[(c4 * 4 + 1) * 520 + row] = (_Float16)expf(v.y);
      sm.Lt[(c4 * 4 + 2) * 520 + row] = (_Float16)expf(v.z);
      sm.Lt[(c4 * 4 + 3) * 520 + row] = (_Float16)expf(v.w);
    }
    __syncthreads();
    int srow = tid >> 4, seg = tid & 15;
    _Float16* dst = Pt + (size_t)(s0 + srow) * 512 + seg * 32;
    const _Float16* lsrc = &sm.Lt[srow * 520 + seg * 32];
#pragma unroll
    for (int q = 0; q < 4; ++q)
      *(half8*)(dst + q * 8) = *(const half8*)(lsrc + q * 8);
  } else if (blk < 1280) {
    // ---- normalize x -> xh ----
    int b = blk - 1024;
    const float4* row = (const float4*)(in0 + (size_t)b * NF);
    float4 v0 = row[tid], v1 = row[tid + 256];
    float ss = v0.x * v0.x + v0.y * v0.y + v0.z * v0.z + v0.w * v0.w +
               v1.x * v1.x + v1.y * v1.y + v1.z * v1.z + v1.w * v1.w;
    float w = waveSum(ss);
    if (lane == 0) sm.s.redA[wave] = w;
    __syncthreads();
    float tot = (sm.s.redA[0] + sm.s.redA[1]) + (sm.s.redA[2] + sm.s.redA[3]);
    float inv = 1.0f / fmaxf(sqrtf(tot), 1e-12f);
    half4 h0, h1;
    h0[0] = (_Float16)(v0.x * inv); h0[1] = (_Float16)(v0.y * inv);
    h0[2] = (_Float16)(v0.z * inv); h0[3] = (_Float16)(v0.w * inv);
    h1[0] = (_Float16)(v1.x * inv); h1[1] = (_Float16)(v1.y * inv);
    h1[2] = (_Float16)(v1.z * inv); h1[3] = (_Float16)(v1.w * inv);
    ((half4*)(xh + (size_t)b * NF))[tid] = h0;
    ((half4*)(xh + (size_t)b * NF))[tid + 256] = h1;
  } else {
    // ---- weight rows for batch item b: zero rows {b, 256+b}, then fill ----
    int b = blk - 1280;
    _Float16* rkl = Wp + (size_t)b * 512;
    _Float16* rce = Wp + (size_t)(256 + b) * 512;
    // 2 rows x 512 fp16 = 2 KB = 128 float4
    if (tid < 64) ((float4*)rkl)[tid] = make_float4(0, 0, 0, 0);
    else if (tid < 128) ((float4*)rce)[tid - 64] = make_float4(0, 0, 0, 0);
    __syncthreads();
    if (tid == 0) {
      float d[NK], e[NK];
      int n[NK];
      float s = 0.0f;
      int cnt = 0;
#pragma unroll
      for (int k = 0; k < NK; ++k) {
        d[k] = ndist[b * NK + k];
        n[k] = neighbors[b * NK + k];
        e[k] = expf(d[k] * (1.0f / 0.6f));
        s += e[k];
        cnt += (d[k] <= 2.0f) ? 1 : 0;
      }
      float invs = 1.0f / (2.0f * s);
      float invc = 1.0f / fmaxf((float)cnt, 1.0f);
#pragma unroll
      for (int k = 0; k < NK; ++k) {
        bool first = true;
#pragma unroll
        for (int k2 = 0; k2 < NK; ++k2)
          if (k2 < k && n[k2] == n[k]) first = false;
        if (first) {
          float wsum = 0.0f, ksum = 0.0f;
#pragma unroll
          for (int k2 = 0; k2 < NK; ++k2)
            if (k2 >= k && n[k2] == n[k]) {
              wsum += e[k2] * invs;
              ksum += (d[k2] <= 2.0f) ? invc : 0.0f;
            }
          rkl[n[k]] = (_Float16)ksum;
          rce[n[k]] = (_Float16)wsum;
          rce[256 + n[k]] = (_Float16)wsum;
        }
      }
    }
  }
}

// ============ K2: both GEMMs ============
// blocks [0,256): scores = x@F^T (128x64 tile, BK=128); B = fp32 features
//   reg-staged->fp16 LDS in ONE load window per iter; outF copy split by
//   K-half across the two by-blocks. Fused stripe-LSE + target pick.
// blocks [256,512): T = W@P fused CE/KL epilogue (128x128, BK=64, alpha B-scale)
__global__ __launch_bounds__(256) void gemms(
    const _Float16* __restrict__ xh, const float* __restrict__ fB,
    const _Float16* __restrict__ Wp, const _Float16* __restrict__ Pt,
    const _Float16* __restrict__ alpha_h,
    const float* __restrict__ logits0, const float* __restrict__ logits1,
    const float* __restrict__ mll, const int* __restrict__ targets,
    float* __restrict__ outF, float* __restrict__ pm, float* __restrict__ pl,
    float* __restrict__ tgt, float* __restrict__ part) {
  __shared__ alignas(16) _Float16 As[128 * 128];  // GEMM1: 128x128; GEMM2 uses 128x64
  __shared__ alignas(16) _Float16 Bs[128 * 64];   // GEMM1: 64x128; GEMM2: 128x64
  __shared__ alignas(16) _Float16 Al[512];
  __shared__ float red[4];
  int tid = threadIdx.x, wave = tid >> 6, lane = tid & 63;
  int quad = lane >> 4, r16 = lane & 15, lrow = lane >> 3, lch = lane & 7;
  int blk = blockIdx.x;
  if (blk < 256) {
    int bx = blk & 127, by = blk >> 7;
    int n0 = bx * 64, m0 = by * 128;
    int rr = tid >> 4, cc = tid & 15;  // staging coords: row-sub, col-block(8 el)
    f32x4 acc[2][4] = {};
    for (int k0 = 0; k0 < NF; k0 += 128) {
      __syncthreads();
      // --- one load window: B fp32 reg loads + A async16, drained together ---
      float4 bv[4][2];
#pragma unroll
      for (int ss = 0; ss < 4; ++ss) {
        int row = ss * 16 + rr;
        int sc = cc ^ (row & 7);
        const float* src = fB + (size_t)(n0 + row) * NF + k0 + sc * 8;
        bv[ss][0] = *(const float4*)src;
        bv[ss][1] = *(const float4*)(src + 4);
      }
#pragma unroll
      for (int ss = 0; ss < 8; ++ss) {
        int row = ss * 16 + rr;
        int sc = cc ^ (row & 7);
        async16(xh + (size_t)(m0 + row) * NF + k0 + sc * 8, &As[row * 128 + cc * 8]);
      }
      bool doStore = (by == ((k0 >= NF / 2) ? 1 : 0));
#pragma unroll
      for (int ss = 0; ss < 4; ++ss) {
        int row = ss * 16 + rr;
        int sc = cc ^ (row & 7);
        half8 h;
        h[0] = (_Float16)bv[ss][0].x; h[1] = (_Float16)bv[ss][0].y;
        h[2] = (_Float16)bv[ss][0].z; h[3] = (_Float16)bv[ss][0].w;
        h[4] = (_Float16)bv[ss][1].x; h[5] = (_Float16)bv[ss][1].y;
        h[6] = (_Float16)bv[ss][1].z; h[7] = (_Float16)bv[ss][1].w;
        *(half8*)&Bs[row * 128 + cc * 8] = h;
        if (doStore) {
          float4* o = (float4*)(outF + (size_t)(n0 + row) * NF + k0 + sc * 8);
          o[0] = bv[ss][0];
          o[1] = bv[ss][1];
        }
      }
      __syncthreads();
#pragma unroll
      for (int sub = 0; sub < 4; ++sub) {
        int slot = ((sub * 4 + quad) ^ (r16 & 7)) * 8;
        half8 af[2], bf[4];
#pragma unroll
        for (int i = 0; i < 2; ++i)
          af[i] = *(const half8*)&As[(wave * 32 + i * 16 + r16) * 128 + slot];
#pragma unroll
        for (int j = 0; j < 4; ++j)
          bf[j] = *(const half8*)&Bs[(j * 16 + r16) * 128 + slot];
#pragma unroll
        for (int i = 0; i < 2; ++i)
#pragma unroll
          for (int j = 0; j < 4; ++j)
            acc[i][j] = __builtin_amdgcn_mfma_f32_16x16x32_f16(af[i], bf[j], acc[i][j], 0, 0, 0);
      }
    }
#pragma unroll
    for (int i = 0; i < 2; ++i)
#pragma unroll
      for (int r = 0; r < 4; ++r) {
        int R = m0 + wave * 32 + i * 16 + quad * 4 + r;
        float sv[4];
#pragma unroll
        for (int j = 0; j < 4; ++j) sv[j] = acc[i][j][r] * 20.0f;  // 1/TEMP
        float mx = fmaxf(fmaxf(sv[0], sv[1]), fmaxf(sv[2], sv[3]));
#pragma unroll
        for (int m2 = 1; m2 < 16; m2 <<= 1) mx = fmaxf(mx, __shfl_xor(mx, m2, 64));
        float e = expf(sv[0] - mx) + expf(sv[1] - mx) + expf(sv[2] - mx) + expf(sv[3] - mx);
#pragma unroll
        for (int m2 = 1; m2 < 16; m2 <<= 1) e += __shfl_xor(e, m2, 64);
        int tg = targets[R];
#pragma unroll
        for (int j = 0; j < 4; ++j)
          if (n0 + j * 16 + r16 == tg) tgt[R] = sv[j];
        if (r16 == 0) { pm[R * 128 + bx] = mx; pl[R * 128 + bx] = e; }
      }
  } else {
    int nb = blk - 256;
    int bx = nb & 63, by = nb >> 6;
    int n0 = bx * 128, m0 = by * 128;
    int wm = (wave >> 1) * 64, wn = (wave & 1) * 64;
    if (tid < 64) ((half8*)Al)[tid] = ((const half8*)alpha_h)[tid];
    f32x4 acc[4][4] = {};
    for (int k0 = 0; k0 < 512; k0 += 64) {
      __syncthreads();
#pragma unroll
      for (int ss = 0; ss < 4; ++ss) {
        int rl = ss * 32 + wave * 8 + lrow;
        int sc = lch ^ (rl & 7);
        async16(Wp + (size_t)(m0 + rl) * 512 + k0 + sc * 8, &As[rl * 64 + lch * 8]);
        async16(Pt + (size_t)(n0 + rl) * 512 + k0 + sc * 8, &Bs[rl * 64 + lch * 8]);
      }
      __syncthreads();
#pragma unroll
      for (int sub = 0; sub < 2; ++sub) {
        int slot = ((sub * 4 + quad) ^ (r16 & 7)) * 8;
        half8 alv = *(const half8*)&Al[k0 + slot];
        half8 af[4], bf[4];
#pragma unroll
        for (int i = 0; i < 4; ++i)
          af[i] = *(const half8*)&As[(wm + i * 16 + r16) * 64 + slot];
#pragma unroll
        for (int j = 0; j < 4; ++j)
          bf[j] = *(const half8*)&Bs[(wn + j * 16 + r16) * 64 + slot] * alv;
#pragma unroll
        for (int i = 0; i < 4; ++i)
#pragma unroll
          for (int j = 0; j < 4; ++j)
            acc[i][j] = __builtin_amdgcn_mfma_f32_16x16x32_f16(af[i], bf[j], acc[i][j], 0, 0, 0);
      }
    }
    bool iskl = (by < 2);
    const float* lgbase = iskl ? logits1 : logits0;
    float local = 0.0f;
#pragma unroll
    for (int i = 0; i < 4; ++i)
#pragma unroll
      for (int r = 0; r < 4; ++r) {
        int Mg = m0 + wm + i * 16 + quad * 4 + r;
        int b = iskl ? Mg : (Mg - 256);
        float mv = mll[iskl ? 256 + b : b];
        const float* lgrow = lgbase + (size_t)b * NS + n0 + wn;
#pragma unroll
        for (int j = 0; j < 4; ++j) {
          float lg = lgrow[j * 16 + r16];
          float t = acc[i][j][r] * (1.0f / 256.0f);
          if (iskl)
            local += (t > 0.0f) ? t * (logf(fmaxf(t, 1e-12f)) - (lg - mv)) : 0.0f;
          else
            local += -0.1f * t * (lg - mv);
        }
      }
    float wsv = waveSum(local);
    if (lane == 0) red[wave] = wsv;
    __syncthreads();
    if (tid == 0) part[nb] = (red[0] + red[1]) + (red[2] + red[3]);
  }
}

// ============ K3: finalize + momentum winner rows ============
__global__ __launch_bounds__(128) void final_reduce(
    const float* __restrict__ pm, const float* __restrict__ pl,
    const float* __restrict__ tgt, const float* __restrict__ part,
    const float* __restrict__ logits0, const float* __restrict__ mll,
    const int* __restrict__ targets, const float* __restrict__ rampup,
    const float* __restrict__ in0, const float* __restrict__ features,
    float* __restrict__ outF, float* __restrict__ out) {
  __shared__ float rA[2], rB[2];
  __shared__ int flag;
  int tid = threadIdx.x, blk = blockIdx.x;
  if (blk < 256) {
    int b = blk;
    float m = pm[b * 128 + tid];
    float l = pl[b * 128 + tid];
    float wm = waveMax(m);
    if ((tid & 63) == 0) rA[tid >> 6] = wm;
    __syncthreads();
    float mx = fmaxf(rA[0], rA[1]);
    float e = l * expf(m - mx);
    float ws = waveSum(e);
    if ((tid & 63) == 0) rB[tid >> 6] = ws;
    __syncthreads();
    if (tid == 0) {
      float S = rB[0] + rB[1];
      float nce = -(tgt[b] - mx - logf(S));
      int tg = targets[b];
      float oh = -0.9f * (logits0[(size_t)b * NS + tg] - mll[b]);
      float pb = part[b];
      float v1 = oh;
      if (b >= 128) v1 += pb;  // CE partials live at part[128..255]
      atomicAdd(out + 0, nce * (1.0f / 256.0f));
      atomicAdd(out + 1, v1 * (1.0f / 256.0f));
      if (b < 128) atomicAdd(out + 2, rampup[0] * pb * (1.0f / 256.0f));
    }
  } else {
    int b = blk - 256;
    int tg = targets[b];
    if (tid == 0) flag = 0;
    __syncthreads();
    bool later = false;
    for (int i = b + 1 + tid; i < 256; i += 128) later = later || (targets[i] == tg);
    if (later) flag = 1;
    __syncthreads();
    if (flag) return;  // some later batch row owns this target
    const float4* xr = (const float4*)(in0 + (size_t)b * NF);
    const float4* fr = (const float4*)(features + (size_t)tg * NF);
    float4 a[4];
    float ssx = 0.0f;
#pragma unroll
    for (int s = 0; s < 4; ++s) {
      a[s] = xr[tid + s * 128];
      ssx += a[s].x * a[s].x + a[s].y * a[s].y + a[s].z * a[s].z + a[s].w * a[s].w;
    }
    float w1 = waveSum(ssx);
    if ((tid & 63) == 0) rA[tid >> 6] = w1;
    __syncthreads();
    float ix = 0.8f / fmaxf(sqrtf(rA[0] + rA[1]), 1e-12f);
    float4 v[4];
    float ss = 0.0f;
#pragma unroll
    for (int s = 0; s < 4; ++s) {
      float4 f = fr[tid + s * 128];
      v[s] = make_float4(0.2f * f.x + ix * a[s].x, 0.2f * f.y + ix * a[s].y,
                         0.2f * f.z + ix * a[s].z, 0.2f * f.w + ix * a[s].w);
      ss += v[s].x * v[s].x + v[s].y * v[s].y + v[s].z * v[s].z + v[s].w * v[s].w;
    }
    float w2 = waveSum(ss);
    if ((tid & 63) == 0) rB[tid >> 6] = w2;
    __syncthreads();
    float inv = 1.0f / fmaxf(sqrtf(rB[0] + rB[1]), 1e-12f);
    float4* o4 = (float4*)(outF + (size_t)tg * NF);
#pragma unroll
    for (int s = 0; s < 4; ++s)
      o4[tid + s * 128] = make_float4(v[s].x * inv, v[s].y * inv, v[s].z * inv, v[s].w * inv);
  }
}

extern "C" void kernel_launch(void* const* d_in, const int* in_sizes, int n_in,
                              void* d_out, int out_size, void* d_ws, size_t ws_size,
                              hipStream_t stream) {
  const float* inputs0 = (const float*)d_in[0];
  const float* logits0 = (const float*)d_in[1];
  const float* logits1 = (const float*)d_in[2];
  const int* targets = (const int*)d_in[3];
  const int* neighbors = (const int*)d_in[5];
  const float* ndist = (const float*)d_in[6];
  const float* rampup = (const float*)d_in[7];
  const float* features = (const float*)d_in[8];
  float* out = (float*)d_out;

  char* ws = (char*)d_ws;
  float* mll = (float*)(ws + 4096);             // 2 KB
  _Float16* alpha_h = (_Float16*)(ws + 8192);   // 1 KB
  float* part = (float*)(ws + 12288);           // 1 KB
  float* tgt = (float*)(ws + 16384);            // 1 KB
  float* pm = (float*)(ws + 65536);             // 128 KB
  float* pl = (float*)(ws + 196608);            // 128 KB
  _Float16* Wp = (_Float16*)(ws + 524288);      // 512 KB
  _Float16* xh = (_Float16*)(ws + (3 << 20));   // 1 MB
  _Float16* Pt = (_Float16*)(ws + (4 << 20));   // 8 MB

  prep<<<1536, 256, 0, stream>>>(inputs0, logits0, logits1, neighbors, ndist,
                                 Pt, xh, alpha_h, mll, Wp, out);
  gemms<<<512, 256, 0, stream>>>(xh, features, Wp, Pt, alpha_h, logits0, logits1,
                                 mll, targets, out + 3, pm, pl, tgt, part);
  final_reduce<<<512, 128, 0, stream>>>(pm, pl, tgt, part, logits0, mll, targets,
                                        rampup, inputs0, features, out + 3, out);
}